// Round 8
// baseline (196.579 us; speedup 1.0000x reference)
//
#include <hip/hip_runtime.h>

typedef unsigned int u32;
typedef unsigned long long u64;

#define A_TOT    159882
#define BS       2
#define KTOP     1000
#define CAND_CAP 4096
#define HB       4096        // 12-bit histogram buckets per segment
#define ABLK     4096        // anchors per hist/compact slice
#define NBH      40          // slices per image

// ---- workspace layout (bytes) ----
static const size_t HIST12_OFF   = 0;         // u32[8*4096] = 128 KB
static const size_t CCNT_OFF     = 131072;    // u32[8]
static const size_t MAXC_OFF     = 131104;    // u32[2]
static const size_t NV_OFF       = 131112;    // u32[10]
static const size_t F_HIST_OFF   = 131152;    // u32[8]  per-seg hist-done counters
static const size_t F_COMP_OFF   = 131184;    // u32[8]  per-seg compact-done
static const size_t F_SD_OFF     = 131216;    // u32[2]  per-image sortdec-done
static const size_t F_MASK_OFF   = 131224;    // u32[10] per-P mask-done
static const size_t F_SCAN_OFF   = 131264;    // u32[2]  per-image scan-done
static const size_t CHUNKANY_OFF = 131328;    // u64[10*16]
static const size_t KEEPS_OFF    = 132608;    // u64[10*16]
static const size_t ZERO_END     = 133888;    // memset covers [0, ZERO_END)
static const size_t CAND_OFF     = 133888;    // u64[8*4096]
static const size_t LKEY2_OFF    = 396032;    // u64[10*1024]
static const size_t LBOX_OFF     = 477952;    // float4[10*1024] (16B aligned)
static const size_t LSC_OFF      = 641792;    // float[10*1024]
static const size_t RANK_OFF     = 682752;    // u32[10*1024]
static const size_t MASK_OFF     = 723712;    // u64[10*16000]
// total ~1.85 MB

__device__ __forceinline__ int level_of(int a) {
  if (a < 120000) return 0;
  if (a < 150000) return 1;
  if (a < 157500) return 2;
  if (a < 159375) return 3;
  return 4;
}
// #blocks contributing to each level's hist/compact (per image): slices
// intersecting [0,120000),[120000,150000),[150000,157500),[157500,159375)
__device__ __forceinline__ u32 ncontrib(int l) {
  return l == 0 ? 30u : (l == 1 ? 8u : (l == 2 ? 3u : 1u));
}

// monotone decreasing transform: smaller d == larger score
__device__ __forceinline__ u32 dkey(float s) {
  u32 b = __float_as_uint(s);
  return (b & 0x80000000u) ? b : (~b & 0x7FFFFFFFu);
}
__device__ __forceinline__ float dkey_inv(u32 d) {
  u32 b = (d & 0x80000000u) ? d : (~d & 0x7FFFFFFFu);
  return __uint_as_float(b);
}

// agent-scope accessors: cross-block data within the kernel, parallel patterns
// only (rounds 1-6 discipline: serial chains stay on LDS / same-block data).
__device__ __forceinline__ u32 ld_agent_u32(const u32* p) {
  return __hip_atomic_load(p, __ATOMIC_RELAXED, __HIP_MEMORY_SCOPE_AGENT);
}
__device__ __forceinline__ u64 ld_agent_u64(const u64* p) {
  return __hip_atomic_load(p, __ATOMIC_RELAXED, __HIP_MEMORY_SCOPE_AGENT);
}
__device__ __forceinline__ void st_agent_u32(u32* p, u32 v) {
  __hip_atomic_store(p, v, __ATOMIC_RELAXED, __HIP_MEMORY_SCOPE_AGENT);
}
__device__ __forceinline__ void st_agent_u64(u64* p, u64 v) {
  __hip_atomic_store(p, v, __ATOMIC_RELAXED, __HIP_MEMORY_SCOPE_AGENT);
}
__device__ __forceinline__ void st_agent_f4(float4* p, float4 v) {
  union { float4 f; u64 q[2]; } u; u.f = v;
  u64* d = (u64*)p;
  st_agent_u64(d, u.q[0]); st_agent_u64(d + 1, u.q[1]);
}
__device__ __forceinline__ float4 ld_agent_f4(const float4* p) {
  union { float4 f; u64 q[2]; } u;
  const u64* s = (const u64*)p;
  u.q[0] = ld_agent_u64(s); u.q[1] = ld_agent_u64(s + 1);
  return u.f;
}

// dataflow flags: bump = publish (syncthreads drains every thread's agent
// stores to the coherence point — compiler emits vmcnt(0) before s_barrier —
// then one ACQ_REL add); wait = consume. NOT a global barrier: each wait
// targets only its own producers, so phases overlap across blocks.
__device__ __forceinline__ void flag_bump(u32* f) {
  __syncthreads();
  if (threadIdx.x == 0)
    __hip_atomic_fetch_add(f, 1u, __ATOMIC_ACQ_REL, __HIP_MEMORY_SCOPE_AGENT);
}
__device__ __forceinline__ void flag_wait(u32* f, u32 tgt) {
  if (threadIdx.x == 0) {
    while (__hip_atomic_load(f, __ATOMIC_ACQUIRE, __HIP_MEMORY_SCOPE_AGENT) < tgt)
      __builtin_amdgcn_s_sleep(2);
  }
  __syncthreads();
}

// bit-exact replica of reference decode + clip + min-size check
__device__ __forceinline__ void decode_clip(const float* __restrict__ pred,
                                            const float* __restrict__ anch,
                                            const float* __restrict__ vs,
                                            int b, int a,
                                            float& x1c, float& y1c, float& x2c, float& y2c,
                                            bool& valid) {
  const float* pp = pred + ((size_t)b * A_TOT + (size_t)a) * 4;
  const float* aa = anch + (size_t)a * 4;
  float ax1 = aa[0], ay1 = aa[1], ax2 = aa[2], ay2 = aa[3];
  float px = pp[0], py = pp[1], pw = pp[2], ph = pp[3];
  float aw  = __fsub_rn(ax2, ax1);
  float ah  = __fsub_rn(ay2, ay1);
  float acx = __fadd_rn(ax1, __fmul_rn(0.5f, aw));
  float acy = __fadd_rn(ay1, __fmul_rn(0.5f, ah));
  float cx  = __fadd_rn(acx, __fmul_rn(px, aw));
  float cy  = __fadd_rn(acy, __fmul_rn(py, ah));
  float w   = __fmul_rn(expf(pw), aw);
  float h   = __fmul_rn(expf(ph), ah);
  float x1  = __fsub_rn(cx, __fmul_rn(0.5f, w));
  float y1  = __fsub_rn(cy, __fmul_rn(0.5f, h));
  float x2  = __fadd_rn(x1, w);
  float y2  = __fadd_rn(y1, h);
  float Wv = vs[b * 2 + 0], Hv = vs[b * 2 + 1];
  x1c = fminf(fmaxf(x1, 0.0f), Wv);
  y1c = fminf(fmaxf(y1, 0.0f), Hv);
  x2c = fminf(fmaxf(x2, 0.0f), Wv);
  y2c = fminf(fmaxf(y2, 0.0f), Hv);
  valid = (__fsub_rn(x2c, x1c) > 0.001f) && (__fsub_rn(y2c, y1c) > 0.001f);
}

__device__ __forceinline__ void bitonic_u64(u64* arr, int N, int t, int nt) {
  for (int k = 2; k <= N; k <<= 1) {
    for (int j = k >> 1; j > 0; j >>= 1) {
      __syncthreads();
      for (int i = t; i < N; i += nt) {
        int ixj = i ^ j;
        if (ixj > i) {
          u64 x = arr[i], y = arr[ixj];
          bool up = ((i & k) == 0);
          if (up ? (x > y) : (x < y)) { arr[i] = y; arr[ixj] = x; }
        }
      }
    }
  }
  __syncthreads();
}

__device__ __forceinline__ u64 shfl_xor_u64(u64 x, int lanemask) {
  u32 lo = (u32)x, hi = (u32)(x >> 32);
  lo = (u32)__shfl_xor((int)lo, lanemask);
  hi = (u32)__shfl_xor((int)hi, lanemask);
  return ((u64)hi << 32) | (u64)lo;
}

// bitonic sort of 2048 u64 keys: 2/thread over 1024 threads.
__device__ __forceinline__ u64* regsort2048x(u64 v[2], int tid, u64* bufA, u64* bufB) {
  u64* bufs[2] = {bufA, bufB};
  int cur = 0;
  for (int k = 2; k <= 2048; k <<= 1) {
    for (int j = k >> 1; j > 0; j >>= 1) {
      if (j == 1) {
        bool up = (((2 * tid) & k) == 0);
        u64 a = v[0], b2 = v[1];
        bool sw = up ? (a > b2) : (a < b2);
        if (sw) { v[0] = b2; v[1] = a; }
      } else if (j <= 64) {
        int dl = j >> 1;
        bool up = (((2 * tid) & k) == 0);
        bool low = ((tid & dl) == 0);
        bool keepmin = (low == up);
#pragma unroll
        for (int e = 0; e < 2; ++e) {
          u64 o = shfl_xor_u64(v[e], dl);
          v[e] = keepmin ? (v[e] < o ? v[e] : o) : (v[e] > o ? v[e] : o);
        }
      } else {
        u64* B = bufs[cur]; cur ^= 1;
        B[2 * tid] = v[0]; B[2 * tid + 1] = v[1];
        __syncthreads();
#pragma unroll
        for (int e = 0; e < 2; ++e) {
          int i = 2 * tid + e, p = i ^ j;
          u64 o = B[p];
          bool up = ((i & k) == 0);
          bool keepmin = ((i < p) == up);
          v[e] = keepmin ? (v[e] < o ? v[e] : o) : (v[e] > o ? v[e] : o);
        }
      }
    }
  }
  u64* B = bufs[cur];
  B[2 * tid] = v[0]; B[2 * tid + 1] = v[1];
  __syncthreads();
  return B;
}

// =====================================================================
// MEGAKERNEL: 160 blocks x 1024, dataflow-gated phases, zero global barriers.
// LDS ~131 KB -> 1 block/CU; 160 <= 256 CUs -> co-residency guaranteed.
// DAG: hist -> compact -> sortdec -> mask -> scan -> fin (acyclic; image-0 mask
// blocks wait only on sortdec blocks 0-4, image-1 on 5-9 — no cycles).
// =====================================================================
__global__ __launch_bounds__(1024)
void k_mega(const float* __restrict__ pred, const float* __restrict__ obj,
            const float* __restrict__ anch, const float* __restrict__ vs,
            float* __restrict__ out, char* __restrict__ ws) {
  __shared__ __align__(16) char smem[130816];
  __shared__ u32 lcnt[2], gbase[2], cutL[2];
  int tid = threadIdx.x, lane = tid & 63;
  int bid = blockIdx.x;
  u32* FH = (u32*)(ws + F_HIST_OFF);
  u32* FC = (u32*)(ws + F_COMP_OFF);
  u32* FS = (u32*)(ws + F_SD_OFF);
  u32* FM = (u32*)(ws + F_MASK_OFF);
  u32* FN = (u32*)(ws + F_SCAN_OFF);

  // ---------------- duty 1: hist + compact (blocks 0..79) ----------------
  if (bid < 80) {
    int b = bid / NBH, loc = bid % NBH;
    int start = loc * ABLK;
    int l0 = level_of(start);
    if (l0 < 4) {
      u32* h  = (u32*)smem;              // 32 KB
      u32* dk = (u32*)(smem + 32768);    // 16 KB dkey cache
      int lend = level_of(min(start + ABLK - 1, A_TOT - 1));
      int nseg = ((l0 + 1 <= lend) && (l0 + 1 < 4)) ? 2 : 1;
      for (int i = tid; i < 2 * HB; i += 1024) h[i] = 0u;
      __syncthreads();
#pragma unroll
      for (int it = 0; it < 4; ++it) {
        int a = start + it * 1024 + tid;
        u32 d = 0;
        if (a < A_TOT) {
          d = dkey(obj[(size_t)b * A_TOT + a]);
          int l = level_of(a);
          if (l < 4) atomicAdd(&h[(u32)(l - l0) * HB + (d >> 20)], 1u);
        }
        dk[it * 1024 + tid] = d;
      }
      __syncthreads();
      for (int s = 0; s < nseg; ++s) {
        u32* gh = (u32*)(ws + HIST12_OFF) + (size_t)(b * 4 + l0 + s) * HB;
        for (int i = tid; i < HB; i += 1024) {
          u32 v = h[s * HB + i];
          if (v) atomicAdd(&gh[i], v);   // device-scope: coherent across XCDs
        }
      }
      __syncthreads();   // drains the hist atomics (vmcnt) before publishing
      if (tid == 0)
        for (int s = 0; s < nseg; ++s)
          __hip_atomic_fetch_add(FH + b * 4 + l0 + s, 1u, __ATOMIC_ACQ_REL,
                                 __HIP_MEMORY_SCOPE_AGENT);
      // wait only THIS block's segments' hists
      for (int s = 0; s < nseg; ++s)
        flag_wait(FH + b * 4 + l0 + s, ncontrib(l0 + s));
      // per-block cutoff from global hist (redundant across blocks, proven cheap)
      u32* scanS = (u32*)(smem + 49152);
      for (int s = 0; s < nseg; ++s) {
        int seg = b * 4 + l0 + s;
        const u32* gh = (const u32*)(ws + HIST12_OFF) + (size_t)seg * HB;
        u32 vals[16]; u32 acc = 0;
        if (tid < 256) {
          for (int q = 0; q < 16; ++q) { vals[q] = ld_agent_u32(&gh[tid * 16 + q]); acc += vals[q]; }
          scanS[tid] = acc;
        }
        __syncthreads();
        for (int d = 1; d < 256; d <<= 1) {
          u32 x = (tid < 256 && tid >= d) ? scanS[tid - d] : 0u;
          __syncthreads();
          if (tid < 256) scanS[tid] += x;
          __syncthreads();
        }
        if (tid < 256) {
          u32 incl = scanS[tid], prev = incl - acc;
          if (prev < KTOP && incl >= KTOP) {   // exactly one thread
            u32 run = prev; int cb = HB - 1;
            for (int q = 0; q < 16; ++q) { run += vals[q]; if (run >= KTOP) { cb = tid * 16 + q; break; } }
            cutL[s] = (u32)cb;
          }
        }
        __syncthreads();
      }
      if (tid < 2) lcnt[tid] = 0;
      __syncthreads();
      // compact from the LDS dkey cache
      u32 dv[4], slotv[4], passm = 0, sim = 0;
#pragma unroll
      for (int it = 0; it < 4; ++it) {
        int a = start + it * 1024 + tid;
        bool pass = false; u32 si = 0;
        u32 d = dk[it * 1024 + tid];
        if (a < A_TOT) {
          int l = level_of(a);
          if (l < 4) { si = (u32)(l - l0); pass = (d >> 20) <= cutL[si]; }
        }
        dv[it] = d;
        u64 mp = __ballot(pass);
        u64 m1 = __ballot(pass && si == 1);
        u64 m0 = mp & ~m1;
        u32 slot = 0;
        if (m0) {
          int ld = __builtin_ctzll(m0);
          u32 wb = 0;
          if (lane == ld) wb = atomicAdd(&lcnt[0], (u32)__popcll(m0));
          wb = __shfl(wb, ld);
          if (pass && si == 0) slot = wb + (u32)__popcll(m0 & ((1ull << lane) - 1ull));
        }
        if (m1) {
          int ld = __builtin_ctzll(m1);
          u32 wb = 0;
          if (lane == ld) wb = atomicAdd(&lcnt[1], (u32)__popcll(m1));
          wb = __shfl(wb, ld);
          if (pass && si == 1) slot = wb + (u32)__popcll(m1 & ((1ull << lane) - 1ull));
        }
        slotv[it] = slot;
        if (pass) { passm |= 1u << it; if (si) sim |= 1u << it; }
      }
      __syncthreads();
      if (tid < 2)
        gbase[tid] = lcnt[tid] ? atomicAdd((u32*)(ws + CCNT_OFF) + (b * 4 + l0 + tid), lcnt[tid]) : 0u;
      __syncthreads();
#pragma unroll
      for (int it = 0; it < 4; ++it) {
        if ((passm >> it) & 1u) {
          int a = start + it * 1024 + tid;
          u32 si = (sim >> it) & 1u;
          int seg = b * 4 + l0 + (int)si;
          u32 gslot = gbase[si] + slotv[it];
          if (gslot < CAND_CAP)
            st_agent_u64((u64*)(ws + CAND_OFF) + (size_t)seg * CAND_CAP + gslot,
                         ((u64)dv[it] << 32) | ((u64)(u32)a << 12) | (u64)gslot);
        }
      }
      __syncthreads();   // drains cand stores before publishing
      if (tid == 0)
        for (int s = 0; s < nseg; ++s)
          __hip_atomic_fetch_add(FC + b * 4 + l0 + s, 1u, __ATOMIC_ACQ_REL,
                                 __HIP_MEMORY_SCOPE_AGENT);
    }
  }

  // ---------------- duty 2: sortdec (blocks 0..9, P = bid) ----------------
  if (bid < 10) {
    u64*    bufAB  = (u64*)smem;               // 32 KB
    float4* dboxS  = (float4*)(smem + 32768);  // 32 KB
    float*  dscS   = (float*)(smem + 65536);   //  8 KB
    u32*    validS = (u32*)(smem + 73728);     //  8 KB
    u64*    cm     = (u64*)(smem + 81920);     // 128 B
    u64* bufA = bufAB; u64* bufB = bufAB + 2048;
    int wv = tid >> 6;
    int P = bid, b = P / 5, l = P % 5;
    if (l < 4) flag_wait(FC + b * 4 + l, ncontrib(l));
    else __syncthreads();   // uniform per block; harmless
    int n;
    u64* S;
    if (l == 4) {
      n = 507;
      u64 v[2];
#pragma unroll
      for (int e = 0; e < 2; ++e) {
        int idx = 2 * tid + e;
        if (idx < 507) {
          int a = 159375 + idx;
          float sc = obj[(size_t)b * A_TOT + a];
          float x1, y1, x2, y2; bool valid;
          decode_clip(pred, anch, vs, b, a, x1, y1, x2, y2, valid);
          dboxS[idx] = make_float4(x1, y1, x2, y2);
          dscS[idx] = sc;
          validS[idx] = valid ? 1u : 0u;
          v[e] = ((u64)dkey(sc) << 32) | ((u64)(u32)a << 12) | (u64)idx;
        } else v[e] = ~0ull;
      }
      S = regsort2048x(v, tid, bufA, bufB);
    } else {
      n = KTOP;
      int seg = b * 4 + l;
      u32 cnt = min(ld_agent_u32((const u32*)(ws + CCNT_OFF) + seg), (u32)CAND_CAP);
      const u64* cand = (const u64*)(ws + CAND_OFF) + (size_t)seg * CAND_CAP;
      if (cnt <= 2048) {
        u64 v[2];
#pragma unroll
        for (int e = 0; e < 2; ++e) {
          int idx = 2 * tid + e;
          if (idx < (int)cnt) {
            u64 key = ld_agent_u64(&cand[idx]);   // parallel gather: agent OK
            int a = (int)((key >> 12) & 0x3FFFFu);
            float x1, y1, x2, y2; bool valid;
            decode_clip(pred, anch, vs, b, a, x1, y1, x2, y2, valid);
            dboxS[idx] = make_float4(x1, y1, x2, y2);
            dscS[idx] = dkey_inv((u32)(key >> 32));
            validS[idx] = valid ? 1u : 0u;
            v[e] = key;
          } else v[e] = ~0ull;
        }
        S = regsort2048x(v, tid, bufA, bufB);
      } else {
        int N = 2048; while (N < (int)cnt) N <<= 1;
        for (int i = tid; i < N; i += 1024)
          bufAB[i] = (i < (int)cnt) ? ld_agent_u64(&cand[i]) : ~0ull;
        bitonic_u64(bufAB, N, tid, 1024);
        for (int j = tid; j < KTOP; j += 1024) {
          u64 key = bufAB[j];
          int a = (int)((key >> 12) & 0x3FFFFu);
          float x1, y1, x2, y2; bool valid;
          decode_clip(pred, anch, vs, b, a, x1, y1, x2, y2, valid);
          dboxS[j] = make_float4(x1, y1, x2, y2);
          dscS[j] = dkey_inv((u32)(key >> 32));
          validS[j] = valid ? 1u : 0u;
          bufAB[j] = (key & ~0xFFFull) | (u64)j;
        }
        __syncthreads();
        S = bufAB;
      }
    }
    float m = 0.0f;
    for (int j = tid; j < n; j += 1024) {
      int slot = (int)(S[j] & 0xFFFull);
      float4 bx = dboxS[slot];
      m = fmaxf(m, fmaxf(fmaxf(bx.x, bx.y), fmaxf(bx.z, bx.w)));
    }
    for (int off = 32; off; off >>= 1) m = fmaxf(m, __shfl_xor(m, off));
    if (lane == 0) atomicMax((u32*)(ws + MAXC_OFF) + b, __float_as_uint(m));
    {
      int j = wv * 64 + lane;
      bool val = (j < n) && (validS[(int)(S[j] & 0xFFFull)] != 0u);
      u64 mask = __ballot(val);
      if (lane == 0) cm[wv] = mask;
      __syncthreads();
      int base = 0;
      for (int w2 = 0; w2 < wv; ++w2) base += __popcll(cm[w2]);
      if (val) {
        int r = base + __popcll(mask & ((1ull << lane) - 1ull));
        int slot = (int)(S[j] & 0xFFFull);
        st_agent_u64((u64*)(ws + LKEY2_OFF) + (size_t)P * 1024 + r, S[j]);
        st_agent_f4((float4*)(ws + LBOX_OFF) + (size_t)P * 1024 + r, dboxS[slot]);
        st_agent_u32((u32*)(ws + LSC_OFF) + (size_t)P * 1024 + r,
                     __float_as_uint(dscS[slot]));
      }
      if (tid == 0) {
        int tot = 0;
        for (int w2 = 0; w2 < 16; ++w2) tot += __popcll(cm[w2]);
        st_agent_u32((u32*)(ws + NV_OFF) + P, (u32)tot);
      }
    }
    flag_bump(FS + b);
  }

  // ---------------- duty 3: mask + rank (all 160: P = bid>>4, rseg = bid&15) ----------------
  int P = bid >> 4, rseg = bid & 15;
  int mb = P / 5, ml = P % 5;
  flag_wait(FS + mb, 5);   // all 5 levels of this image decoded (maxc, nv final)
  int n = (int)ld_agent_u32((const u32*)(ws + NV_OFF) + P);
  int W = (n + 63) >> 6;
  {
    float4* boxS  = (float4*)smem;            // 16 KB
    float*  areaS = (float*)(smem + 16384);   //  4 KB
    u64*    lkeyS = (u64*)(smem + 20480);     // 32 KB: 4 other levels' keys
    u32*    nvO   = (u32*)(smem + 53248);     // 16 B
    float M = __uint_as_float(ld_agent_u32((const u32*)(ws + MAXC_OFF) + mb));
    float off = __fmul_rn((float)ml, __fadd_rn(M, 1.0f));
    const float4* lbox = (const float4*)(ws + LBOX_OFF) + (size_t)P * 1024;
    for (int i = tid; i < n; i += 1024) {
      float4 bx = ld_agent_f4(&lbox[i]);
      bx.x = __fadd_rn(bx.x, off); bx.y = __fadd_rn(bx.y, off);
      bx.z = __fadd_rn(bx.z, off); bx.w = __fadd_rn(bx.w, off);
      boxS[i] = bx;
      areaS[i] = __fmul_rn(__fsub_rn(bx.z, bx.x), __fsub_rn(bx.w, bx.y));
    }
    if (tid < 4) {
      int l2 = tid + (tid >= ml ? 1 : 0);
      nvO[tid] = ld_agent_u32((const u32*)(ws + NV_OFF) + mb * 5 + l2);
    }
    for (int t = tid; t < 4096; t += 1024) {   // stage other levels' keys to LDS
      int q = t >> 10, i = t & 1023;
      int l2 = q + (q >= ml ? 1 : 0);
      lkeyS[t] = ld_agent_u64((const u64*)(ws + LKEY2_OFF) + (size_t)(mb * 5 + l2) * 1024 + i);
    }
    __syncthreads();
    // merged rank: 64 elements of this block, binary search on LDS-staged keys
    if (tid < 64) {
      int e = rseg * 64 + tid;
      if (e < n) {
        u64 key = ld_agent_u64((const u64*)(ws + LKEY2_OFF) + (size_t)P * 1024 + e);
        int lo[4], hi[4];
#pragma unroll
        for (int q = 0; q < 4; ++q) { lo[q] = 0; hi[q] = (int)nvO[q]; }
        for (int step = 0; step < 11; ++step) {
#pragma unroll
          for (int q = 0; q < 4; ++q) {
            if (lo[q] < hi[q]) {
              int mid = (lo[q] + hi[q]) >> 1;
              u64 v = lkeyS[q * 1024 + mid];
              if (v < key) lo[q] = mid + 1; else hi[q] = mid;
            }
          }
        }
        st_agent_u32((u32*)(ws + RANK_OFF) + (size_t)P * 1024 + e,
                     (u32)(e + lo[0] + lo[1] + lo[2] + lo[3]));
      }
    }
    __syncthreads();
    // triangle IoU mask for rows [rseg*64, rseg*64+64) (verified rounds 3/5/6)
    int i = rseg * 64 + (tid >> 4);
    int w = tid & 15;
    if (i < n && w < W && w >= rseg) {
      float4 bi = boxS[i];
      float ai = areaS[i];
      u64 word = 0;
      int j0 = w << 6;
      int jn = min(64, n - j0);
      if (jn == 64) {
#pragma unroll 4
        for (int t2 = 0; t2 < 64; ++t2) {
          int jj = (t2 + w) & 63;      // bank-conflict-free rotation
          float4 bj = boxS[j0 + jj];
          float xx1 = fmaxf(bi.x, bj.x);
          float yy1 = fmaxf(bi.y, bj.y);
          float xx2 = fminf(bi.z, bj.z);
          float yy2 = fminf(bi.w, bj.w);
          float iw = fmaxf(__fsub_rn(xx2, xx1), 0.0f);
          float ih = fmaxf(__fsub_rn(yy2, yy1), 0.0f);
          float inter = __fmul_rn(iw, ih);
          float den = __fadd_rn(__fsub_rn(__fadd_rn(ai, areaS[j0 + jj]), inter), 1e-9f);
          float iou = __fdiv_rn(inter, den);
          if (iou > 0.7f) word |= (1ull << jj);
        }
      } else {
        for (int jj = 0; jj < jn; ++jj) {
          float4 bj = boxS[j0 + jj];
          float xx1 = fmaxf(bi.x, bj.x);
          float yy1 = fmaxf(bi.y, bj.y);
          float xx2 = fminf(bi.z, bj.z);
          float yy2 = fminf(bi.w, bj.w);
          float iw = fmaxf(__fsub_rn(xx2, xx1), 0.0f);
          float ih = fmaxf(__fsub_rn(yy2, yy1), 0.0f);
          float inter = __fmul_rn(iw, ih);
          float den = __fadd_rn(__fsub_rn(__fadd_rn(ai, areaS[j0 + jj]), inter), 1e-9f);
          float iou = __fdiv_rn(inter, den);
          if (iou > 0.7f) word |= (1ull << jj);
        }
      }
      if (w == rseg) word &= ~(1ull << (i & 63));   // zero diagonal
      st_agent_u64((u64*)(ws + MASK_OFF) + (size_t)P * 16000 + (size_t)i * W + w, word);
      if (word)
        atomicOr((u64*)(ws + CHUNKANY_OFF) + (size_t)P * 16 + (i >> 6), 1ull << (i & 63));
    }
  }
  flag_bump(FM + P);
  if (rseg != 15) return;

  // ---------------- duty 4: serial NMS scan (16th block of each P) ----------------
  flag_wait(FM + P, 16);
  {
    u64* maskL = (u64*)smem;   // 125 KB, aliases mask-phase LDS (already consumed)
    const u64* maskg = (const u64*)(ws + MASK_OFF) + (size_t)P * 16000;
    int T = n * W;
    for (int t = tid; t < T; t += 1024) maskL[t] = ld_agent_u64(&maskg[t]);  // parallel stage
    __syncthreads();
    if (tid < 64) {
      u64 ca = (lane < 16)
                 ? ld_agent_u64((const u64*)(ws + CHUNKANY_OFF) + (size_t)P * 16 + lane)
                 : 0ull;
      u64 dpre[16];
#pragma unroll
      for (int c = 0; c < 16; ++c) {
        int row = (c << 6) + lane;
        dpre[c] = (c < W && row < n) ? maskL[(size_t)row * W + c] : 0ull;
      }
      u64 removed = 0ull, keepw = 0ull;
#pragma unroll
      for (int c = 0; c < 16; ++c) {
        if (c >= W) break;
        int rb = c << 6;
        int rows = min(64, n - rb);
        u64 rowsmask = (rows == 64) ? ~0ull : ((1ull << rows) - 1ull);
        u64 curw = __shfl(removed, c);
        u64 cand = ~curw & rowsmask;
        u64 ca_c = __shfl(ca, c);
        u64 keptbits;
        u64 anyrows = ca_c & cand;
        if (anyrows == 0ull) {
          keptbits = cand;
        } else {
          u64 diag = dpre[c];
          u64 diagnz = __ballot(diag != 0ull) & cand;
          if (diagnz == 0ull) {
            keptbits = cand;
          } else {
            u64 remw = curw | ~rowsmask;
            u64 kept = 0ull;
            int pos = 0;
            u64 work = diagnz;
            while (work) {
              int s = __builtin_ctzll(work); work &= work - 1;
              u64 range = (1ull << s) - (1ull << pos);
              kept |= ~remw & range;
              bool k = ((remw >> s) & 1ull) == 0ull;
              u64 dr = __shfl(diag, s);
              if (k) { kept |= 1ull << s; remw |= dr; }
              pos = s + 1;
            }
            u64 tail = (pos >= 64) ? 0ull : (~0ull << pos);
            kept |= ~remw & tail & rowsmask;
            keptbits = kept;
          }
          u64 todo = keptbits & ca_c;
          while (todo) {
            int r0 = __builtin_ctzll(todo); todo &= todo - 1;
            int r1 = -1, r2 = -1, r3 = -1;
            if (todo) { r1 = __builtin_ctzll(todo); todo &= todo - 1; }
            if (todo) { r2 = __builtin_ctzll(todo); todo &= todo - 1; }
            if (todo) { r3 = __builtin_ctzll(todo); todo &= todo - 1; }
            u64 v0 = 0, v1 = 0, v2 = 0, v3 = 0;
            if (lane < W) {
              v0 = maskL[(size_t)(rb + r0) * W + lane];
              if (r1 >= 0) v1 = maskL[(size_t)(rb + r1) * W + lane];
              if (r2 >= 0) v2 = maskL[(size_t)(rb + r2) * W + lane];
              if (r3 >= 0) v3 = maskL[(size_t)(rb + r3) * W + lane];
            }
            removed |= v0 | v1 | v2 | v3;
          }
        }
        if (lane == c) keepw |= keptbits;
      }
      if (lane < 16)
        st_agent_u64((u64*)(ws + KEEPS_OFF) + (size_t)P * 16 + lane, keepw);
    }
  }
  flag_bump(FN + mb);
  if (ml != 0) return;

  // ---------------- duty 5: cross-level merge + emit (blocks 15 and 95) ----------------
  flag_wait(FN + mb, 5);
  {
    u64* keepsF = (u64*)(smem + 128000);
    u64* kbF    = (u64*)(smem + 128640);
    u32* sbF    = (u32*)(smem + 129280);
    u32* pfxF   = (u32*)(smem + 129792);
    u32* nvsF   = (u32*)(smem + 130112);
    int b = mb;
    for (int i = tid; i < 80; i += 1024) {
      keepsF[i] = ld_agent_u64((const u64*)(ws + KEEPS_OFF) + (size_t)b * 80 + i);
      kbF[i] = 0ull;
    }
    if (tid < 5) nvsF[tid] = ld_agent_u32((const u32*)(ws + NV_OFF) + b * 5 + tid);
    for (int i = tid; i < 4000; i += 1024) out[(size_t)b * 4000 + i] = 0.0f;
    for (int i = tid; i < 1000; i += 1024) out[8000 + (size_t)b * 1000 + i] = 0.0f;
    __syncthreads();
    const u32* rank = (const u32*)(ws + RANK_OFF);
    for (int idx = tid; idx < 5120; idx += 1024) {
      int p = idx >> 10, i = idx & 1023;
      if (i < (int)nvsF[p] && ((keepsF[p * 16 + (i >> 6)] >> (i & 63)) & 1ull)) {
        u32 r = ld_agent_u32(&rank[(size_t)(b * 5 + p) * 1024 + i]);
        atomicOr(&kbF[r >> 6], 1ull << (r & 63));
      }
    }
    __syncthreads();
    if (tid < 128) sbF[tid] = (tid < 80) ? (u32)__popcll(kbF[tid]) : 0u;
    __syncthreads();
    for (int d = 1; d < 128; d <<= 1) {
      u32 x = (tid < 128 && tid >= d) ? sbF[tid - d] : 0u;
      __syncthreads();
      if (tid < 128) sbF[tid] += x;
      __syncthreads();
    }
    if (tid < 80) pfxF[tid] = sbF[tid] - (u32)__popcll(kbF[tid]);
    __syncthreads();
    for (int idx = tid; idx < 5120; idx += 1024) {
      int p = idx >> 10, i = idx & 1023;
      if (i < (int)nvsF[p] && ((keepsF[p * 16 + (i >> 6)] >> (i & 63)) & 1ull)) {
        int Pp = b * 5 + p;
        u32 r = ld_agent_u32(&rank[(size_t)Pp * 1024 + i]);
        u64 word = kbF[r >> 6];
        int slot = (int)pfxF[r >> 6] + __popcll(word & ((1ull << (r & 63)) - 1ull));
        if (slot < KTOP) {
          float4 bx = ld_agent_f4((const float4*)(ws + LBOX_OFF) + (size_t)Pp * 1024 + i);
          float s = __uint_as_float(ld_agent_u32((const u32*)(ws + LSC_OFF) + (size_t)Pp * 1024 + i));
          float* ob = out + ((size_t)b * KTOP + slot) * 4;
          ob[0] = bx.x; ob[1] = bx.y; ob[2] = bx.z; ob[3] = bx.w;
          out[8000 + (size_t)b * KTOP + slot] = s;
        }
      }
    }
  }
}

extern "C" void kernel_launch(void* const* d_in, const int* in_sizes, int n_in,
                              void* d_out, int out_size, void* d_ws, size_t ws_size,
                              hipStream_t stream) {
  const float* pred = (const float*)d_in[0];
  const float* obj  = (const float*)d_in[1];
  const float* anch = (const float*)d_in[2];
  const float* vs   = (const float*)d_in[3];
  float* out = (float*)d_out;
  char* ws = (char*)d_ws;
  (void)in_sizes; (void)n_in; (void)out_size; (void)ws_size;

  hipMemsetAsync(ws, 0, ZERO_END, stream);   // hist + control + flag counters
  k_mega<<<160, 1024, 0, stream>>>(pred, obj, anch, vs, out, ws);
}